// Round 1
// baseline (3484.174 us; speedup 1.0000x reference)
//
#include <hip/hip_runtime.h>

#define NB   256
#define SEQ  4096
#define HID  128
#define G4   512   // 4*HID

// ---------------------------------------------------------------------------
// Kernel A: fold the input projection into one effective weight per gate row.
//   W_eff[g,0..2] = sum_h W_ih[g,h] * W_inp[h,0..2]
//   b_eff[g]      = sum_h W_ih[g,h] * b_inp[h] + b_ih[g] + b_hh[g]
// Packed as float4 {wx, wy, wz, beff} per gate.
// ---------------------------------------------------------------------------
__global__ void precompute_weff(const float* __restrict__ W_inp,   // (64,3)
                                const float* __restrict__ b_inp,   // (64)
                                const float* __restrict__ W_ih,    // (512,64)
                                const float* __restrict__ b_ih,    // (512)
                                const float* __restrict__ b_hh,    // (512)
                                float4* __restrict__ weff)         // (512)
{
    int g = blockIdx.x * blockDim.x + threadIdx.x;
    if (g >= G4) return;
    const float* wrow = W_ih + g * 64;
    float wx = 0.f, wy = 0.f, wz = 0.f, bb = 0.f;
    for (int h = 0; h < 64; ++h) {
        float w = wrow[h];
        wx += w * W_inp[h * 3 + 0];
        wy += w * W_inp[h * 3 + 1];
        wz += w * W_inp[h * 3 + 2];
        bb += w * b_inp[h];
    }
    bb += b_ih[g] + b_hh[g];
    weff[g] = make_float4(wx, wy, wz, bb);
}

__device__ __forceinline__ float fast_sigmoid(float x) {
    return 1.f / (1.f + __expf(-x));
}
__device__ __forceinline__ float fast_tanh(float x) {
    // tanh(x) = 1 - 2/(exp(2x)+1); handles +-inf overflow correctly
    return 1.f - 2.f / (__expf(2.f * x) + 1.f);
}

// ---------------------------------------------------------------------------
// Kernel B: persistent LSTM, one workgroup per batch element (256 wg = 256 CU).
// Thread g (0..511) owns gate row g: 128 W_hh weights live in registers.
// hx lives in LDS (wave-uniform broadcast reads). 2 barriers per step.
// ---------------------------------------------------------------------------
__global__ __launch_bounds__(512, 2)
void lstm_persistent(const float*  __restrict__ inputs,  // (B,S,3)
                     const float*  __restrict__ hx0,     // (B,128)
                     const float*  __restrict__ cx0,     // (B,128)
                     const float*  __restrict__ W_hh,    // (512,128)
                     const float4* __restrict__ weff,    // (512)
                     const float*  __restrict__ W_out,   // (40,128)
                     const float*  __restrict__ b_out,   // (40)
                     float*        __restrict__ out)     // (B,40)
{
    __shared__ float uin[SEQ * 3];                  // 48 KB staged inputs
    __shared__ float gbuf[G4];                      // activated gates
    __shared__ __align__(16) float hxbuf[HID];      // hidden state

    const int b   = blockIdx.x;
    const int tid = threadIdx.x;

    // Stage this batch element's whole input sequence into LDS (one-time).
    {
        const float* src = inputs + (size_t)b * (SEQ * 3);
        for (int i = tid; i < SEQ * 3; i += 512) uin[i] = src[i];
    }

    // Load this gate's recurrent weights into registers (static indexing).
    float4 w4[32];
    {
        const float4* wrow = reinterpret_cast<const float4*>(W_hh + tid * HID);
        #pragma unroll
        for (int k = 0; k < 32; ++k) w4[k] = wrow[k];
    }
    const float4 we = weff[tid];

    // Init state.
    if (tid < HID) hxbuf[tid] = hx0[b * HID + tid];
    float cx = (tid < HID) ? cx0[b * HID + tid] : 0.f;
    __syncthreads();

    const int gtype = tid >> 7;   // 0=i 1=f 2=g 3=o

    for (int s = 0; s < SEQ; ++s) {
        // Input contribution (wave-uniform LDS broadcast reads).
        const float ux = uin[s * 3 + 0];
        const float uy = uin[s * 3 + 1];
        const float uz = uin[s * 3 + 2];

        // 128-长 dot product, 4 independent accumulator chains for ILP.
        float a0 = we.w + we.x * ux;
        float a1 = we.y * uy;
        float a2 = we.z * uz;
        float a3 = 0.f;
        const float4* hx4 = reinterpret_cast<const float4*>(hxbuf);
        #pragma unroll
        for (int k = 0; k < 32; ++k) {
            const float4 h = hx4[k];
            a0 += w4[k].x * h.x;
            a1 += w4[k].y * h.y;
            a2 += w4[k].z * h.z;
            a3 += w4[k].w * h.w;
        }
        const float acc = (a0 + a1) + (a2 + a3);

        // Per-gate activation (each thread applies its own gate's nonlinearity).
        const float act = (gtype == 2) ? fast_tanh(acc) : fast_sigmoid(acc);
        gbuf[tid] = act;
        __syncthreads();   // all gates visible; all hx reads of this step done

        if (tid < HID) {
            const float i_ = gbuf[tid];
            const float f_ = gbuf[tid + 128];
            const float g_ = gbuf[tid + 256];
            const float o_ = gbuf[tid + 384];
            cx = f_ * cx + i_ * g_;
            hxbuf[tid] = o_ * fast_tanh(cx);
            // NOTE: reference's where(all(hx > hx_new)) branch requires all
            // 32768 strict inequalities to hold simultaneously -> never taken.
        }
        __syncthreads();   // new hx visible to everyone
    }

    // Output projection: out[b] = W_out @ hx_last + b_out  (40 outputs)
    if (tid < 40) {
        float acc = b_out[tid];
        const float* wr = W_out + tid * HID;
        #pragma unroll 8
        for (int k = 0; k < HID; ++k) acc += wr[k] * hxbuf[k];
        out[b * 40 + tid] = acc;
    }
}

extern "C" void kernel_launch(void* const* d_in, const int* in_sizes, int n_in,
                              void* d_out, int out_size, void* d_ws, size_t ws_size,
                              hipStream_t stream) {
    const float* inputs = (const float*)d_in[0];
    const float* hx0    = (const float*)d_in[1];
    const float* cx0    = (const float*)d_in[2];
    const float* W_inp  = (const float*)d_in[3];
    const float* b_inp  = (const float*)d_in[4];
    const float* W_ih   = (const float*)d_in[5];
    const float* b_ih   = (const float*)d_in[6];
    const float* W_hh   = (const float*)d_in[7];
    const float* b_hh   = (const float*)d_in[8];
    const float* W_out  = (const float*)d_in[9];
    const float* b_out  = (const float*)d_in[10];
    float* out = (float*)d_out;

    float4* weff = (float4*)d_ws;   // 512 * 16 B = 8 KB scratch

    precompute_weff<<<1, 512, 0, stream>>>(W_inp, b_inp, W_ih, b_ih, b_hh, weff);
    lstm_persistent<<<NB, 512, 0, stream>>>(inputs, hx0, cx0, W_hh, weff,
                                            W_out, b_out, out);
}